// Round 6
// baseline (141.931 us; speedup 1.0000x reference)
//
#include <hip/hip_runtime.h>
#include <hip/hip_bf16.h>

// ---------------------------------------------------------------------------
// UncertaintyAwareQNetwork: E=5 ensemble x NS=10 MC samples, B=4096 rows.
// Pipeline (3 dispatches):
//   prep:   state->bf16, realized weights (32x32x16 MFMA-frag-major) + KL
//   mlp:    fused 3-layer kernel, 128-row x 256-out tile, mfma 32x32x16,
//           2-deep register prefetch, 80 KB LDS (2 blocks/CU), XCD swizzle
//   heads:  ensemble stats + uncertainty/risk heads + KL final
// y2 layout: [es][b][20] f32 -> mlp blocks write contiguous full lines.
// ---------------------------------------------------------------------------

typedef __bf16 bf16x8 __attribute__((ext_vector_type(8)));
typedef float f32x4 __attribute__((ext_vector_type(4)));
typedef float f32x16 __attribute__((ext_vector_type(16)));
typedef unsigned short u16x4 __attribute__((ext_vector_type(4)));
typedef unsigned short u16x8 __attribute__((ext_vector_type(8)));

__device__ __forceinline__ unsigned short f2bf(float f) {
  unsigned int u = __builtin_bit_cast(unsigned int, f);
  u += 0x7fffu + ((u >> 16) & 1u);
  return (unsigned short)(u >> 16);
}

__device__ __forceinline__ float softplus_f(float x) {
  return (x > 20.f) ? x : __logf(1.f + __expf(x));
}

__device__ __forceinline__ float klterm(float m, float sg) {
  return -__logf(sg) + (sg * sg + m * m) * 0.5f - 0.5f;
}

__device__ __forceinline__ f32x16 mfma32(bf16x8 a, bf16x8 b, f32x16 c) {
  return __builtin_amdgcn_mfma_f32_32x32x16_bf16(a, b, c, 0, 0, 0);
}

// ------------------- prep bodies (fused into one kernel) --------------------

__device__ __forceinline__ void scvt_body(int gid, const float* __restrict__ s,
                                          unsigned short* __restrict__ d) {
  const f32x4* p = (const f32x4*)(s + (size_t)gid * 8);
  f32x4 x0 = p[0], x1 = p[1];
  u16x8 v = {f2bf(x0.x), f2bf(x0.y), f2bf(x0.z), f2bf(x0.w),
             f2bf(x1.x), f2bf(x1.y), f2bf(x1.z), f2bf(x1.w)};
  *(u16x8*)(d + (size_t)gid * 8) = v;
}

// 32x32x16 A-frag layout: frag id = (es*(OPAD/32) + osub)*16 + kt2;
// lane l = (o&31) + 32*k_octet holds W[o][k = kt2*16 + k_octet*8 + 0..7].
template <int O, int OPAD>
__device__ __forceinline__ float wgen_body(int gid, const float* __restrict__ wmu,
                                           const float* __restrict__ wrho,
                                           const float* __restrict__ weps,
                                           char* __restrict__ wf) {
  int es = gid / (OPAD * 32);
  int rem = gid - es * (OPAD * 32);
  int o = rem >> 5;
  int i8 = (rem & 31) * 8;
  int e = es / 10, s = es - e * 10;
  float v[8];
  float kl = 0.f;
  if (O == OPAD || o < O) {
    const float* mu = wmu + ((size_t)(e * O + o)) * 256 + i8;
    const float* rho = wrho + ((size_t)(e * O + o)) * 256 + i8;
    const float* eps = weps + ((size_t)((e * 10 + s) * O + o)) * 256 + i8;
    float mv[8], rv[8], ev[8];
    *(f32x4*)(mv) = ((const f32x4*)mu)[0];
    *(f32x4*)(mv + 4) = ((const f32x4*)mu)[1];
    *(f32x4*)(rv) = ((const f32x4*)rho)[0];
    *(f32x4*)(rv + 4) = ((const f32x4*)rho)[1];
    *(f32x4*)(ev) = ((const f32x4*)eps)[0];
    *(f32x4*)(ev + 4) = ((const f32x4*)eps)[1];
#pragma unroll
    for (int j = 0; j < 8; ++j) {
      float m = mv[j];
      float sg = softplus_f(rv[j]);
      v[j] = m + sg * ev[j];
      if (s == 0) kl += klterm(m, sg);
    }
  } else {
#pragma unroll
    for (int j = 0; j < 8; ++j) v[j] = 0.f;
  }
  u16x8 pk = {f2bf(v[0]), f2bf(v[1]), f2bf(v[2]), f2bf(v[3]),
              f2bf(v[4]), f2bf(v[5]), f2bf(v[6]), f2bf(v[7])};
  int osub = o >> 5, om = o & 31, kt2 = i8 >> 4, hi = (i8 >> 3) & 1;
  int lane = om + 32 * hi;
  *(u16x8*)(wf + (size_t)(((es * (OPAD / 32) + osub) * 16 + kt2) * 64 + lane) * 16) = pk;
  return kl;
}

__global__ __launch_bounds__(256) void prep_kernel(
    const float* __restrict__ state, unsigned short* __restrict__ stateb,
    const float* __restrict__ wmu0, const float* __restrict__ wrho0,
    const float* __restrict__ weps0, char* __restrict__ W0f,
    const float* __restrict__ wmu1, const float* __restrict__ wrho1,
    const float* __restrict__ weps1, char* __restrict__ W1f,
    const float* __restrict__ wmu2, const float* __restrict__ wrho2,
    const float* __restrict__ weps2, char* __restrict__ W2f,
    const float* __restrict__ bmu0, const float* __restrict__ brho0,
    const float* __restrict__ beps0, const float* __restrict__ bmu1,
    const float* __restrict__ brho1, const float* __restrict__ beps1,
    const float* __restrict__ bmu2, const float* __restrict__ brho2,
    const float* __restrict__ beps2, float* __restrict__ bias0,
    float* __restrict__ bias1, float* __restrict__ bias2,
    float* __restrict__ partials) {
  int bid = blockIdx.x, t = threadIdx.x;
  float kl = 0.f;
  if (bid < 512) {
    scvt_body(bid * 256 + t, state, stateb);
  } else if (bid < 2112) {
    kl = wgen_body<256, 256>((bid - 512) * 256 + t, wmu0, wrho0, weps0, W0f);
  } else if (bid < 3712) {
    kl = wgen_body<256, 256>((bid - 2112) * 256 + t, wmu1, wrho1, weps1, W1f);
  } else if (bid < 3912) {
    kl = wgen_body<18, 32>((bid - 3712) * 256 + t, wmu2, wrho2, weps2, W2f);
  } else {
    int gid = (bid - 3912) * 256 + t;
    if (gid < 12800) {
      int es = gid >> 8, o = gid & 255, e = es / 10, s = es - e * 10;
      float m = bmu0[e * 256 + o];
      float sg = softplus_f(brho0[e * 256 + o]);
      bias0[gid] = m + sg * beps0[(e * 10 + s) * 256 + o];
      if (s == 0) kl = klterm(m, sg);
    } else if (gid < 25600) {
      int id = gid - 12800;
      int es = id >> 8, o = id & 255, e = es / 10, s = es - e * 10;
      float m = bmu1[e * 256 + o];
      float sg = softplus_f(brho1[e * 256 + o]);
      bias1[id] = m + sg * beps1[(e * 10 + s) * 256 + o];
      if (s == 0) kl = klterm(m, sg);
    } else if (gid < 27200) {
      int id = gid - 25600;
      int es = id >> 5, o = id & 31, e = es / 10, s = es - e * 10;
      if (o < 18) {
        float m = bmu2[e * 18 + o];
        float sg = softplus_f(brho2[e * 18 + o]);
        bias2[id] = m + sg * beps2[(e * 10 + s) * 18 + o];
        if (s == 0) kl = klterm(m, sg);
      } else {
        bias2[id] = 0.f;
      }
    }
  }
  // uniform block reduce of kl partials
#pragma unroll
  for (int m = 32; m >= 1; m >>= 1) kl += __shfl_xor(kl, m);
  __shared__ float wsum[4];
  if ((t & 63) == 0) wsum[t >> 6] = kl;
  __syncthreads();
  if (t == 0) partials[bid] = wsum[0] + wsum[1] + wsum[2] + wsum[3];
}

// ------------------------------ fused MLP ------------------------------------
// Block tile: 128 rows x 256 outs. 8 waves = 2 row-groups (bg) x 4 o-groups
// (og); wave tile 64 outs x 64 rows as 2x2 tiles of 32x32 -> 4 f32x16 acc.
// Activation LDS: 64 frags (bt 0..3 x kt2 0..15), frag = 1 KB, lane*16 linear.
// B-frag: lane l holds x[b = bt*32 + (l&31)][k = kt2*16 + (l>>5)*8 + 0..7].
__device__ __forceinline__ void mlp_layer32(const char* __restrict__ wA,
                                            const float* __restrict__ bias_es,
                                            int og, int bg,
                                            char* __restrict__ buf, int lane) {
  const char* a0p = wA + (size_t)(2 * og) * 16384;
  const char* a1p = a0p + 16384;
  const char* b0p = buf + (2 * bg) * 16384;
  const char* b1p = b0p + 16384;
  int lo = lane * 16;
  f32x16 acc00, acc01, acc10, acc11;
#pragma unroll
  for (int c = 0; c < 16; ++c) {
    acc00[c] = 0.f; acc01[c] = 0.f; acc10[c] = 0.f; acc11[c] = 0.f;
  }

  bf16x8 a0c = *(const bf16x8*)(a0p + lo);
  bf16x8 a1c = *(const bf16x8*)(a1p + lo);
  bf16x8 b0c = *(const bf16x8*)(b0p + lo);
  bf16x8 b1c = *(const bf16x8*)(b1p + lo);
#pragma unroll
  for (int kp = 0; kp < 8; ++kp) {
    bf16x8 a0n = *(const bf16x8*)(a0p + (2 * kp + 1) * 1024 + lo);
    bf16x8 a1n = *(const bf16x8*)(a1p + (2 * kp + 1) * 1024 + lo);
    bf16x8 b0n = *(const bf16x8*)(b0p + (2 * kp + 1) * 1024 + lo);
    bf16x8 b1n = *(const bf16x8*)(b1p + (2 * kp + 1) * 1024 + lo);
    __builtin_amdgcn_s_setprio(1);
    acc00 = mfma32(a0c, b0c, acc00);
    acc01 = mfma32(a0c, b1c, acc01);
    acc10 = mfma32(a1c, b0c, acc10);
    acc11 = mfma32(a1c, b1c, acc11);
    __builtin_amdgcn_s_setprio(0);
    if (kp < 7) {
      a0c = *(const bf16x8*)(a0p + (2 * kp + 2) * 1024 + lo);
      a1c = *(const bf16x8*)(a1p + (2 * kp + 2) * 1024 + lo);
      b0c = *(const bf16x8*)(b0p + (2 * kp + 2) * 1024 + lo);
      b1c = *(const bf16x8*)(b1p + (2 * kp + 2) * 1024 + lo);
    }
    __builtin_amdgcn_s_setprio(1);
    acc00 = mfma32(a0n, b0n, acc00);
    acc01 = mfma32(a0n, b1n, acc01);
    acc10 = mfma32(a1n, b0n, acc10);
    acc11 = mfma32(a1n, b1n, acc11);
    __builtin_amdgcn_s_setprio(0);
  }
  __syncthreads();  // all reads of buf complete before in-place overwrite

  // epilogue: bias+relu+bf16, packed into next layer's B-frag layout.
  // C/D: col b = lane&31, row o_local = (reg&3) + 8*(reg>>2) + 4*(lane>>5).
  int hi = lane >> 5, bcol = lane & 31;
  auto epi = [&](const f32x16& A, int i, int j) {
    int obt = og * 64 + i * 32;
    char* fb = buf + (size_t)((2 * bg + j) * 16) * 1024;
#pragma unroll
    for (int q = 0; q < 4; ++q) {
      int o0 = obt + 8 * q + 4 * hi;
      f32x4 bv = *(const f32x4*)(bias_es + o0);
      float v0 = fmaxf(A[4 * q + 0] + bv.x, 0.f);
      float v1 = fmaxf(A[4 * q + 1] + bv.y, 0.f);
      float v2 = fmaxf(A[4 * q + 2] + bv.z, 0.f);
      float v3 = fmaxf(A[4 * q + 3] + bv.w, 0.f);
      u16x4 pk = {f2bf(v0), f2bf(v1), f2bf(v2), f2bf(v3)};
      int kt2t = o0 >> 4;
      *(u16x4*)(fb + kt2t * 1024 + (bcol + 32 * (q & 1)) * 16 + 8 * hi) = pk;
    }
  };
  epi(acc00, 0, 0);
  epi(acc01, 0, 1);
  epi(acc10, 1, 0);
  epi(acc11, 1, 1);
  __syncthreads();  // writes visible before next layer reads
}

__global__ __launch_bounds__(512, 4) void mlp_fused(
    const unsigned short* __restrict__ stateb, const char* __restrict__ W0f,
    const char* __restrict__ W1f, const char* __restrict__ W2f,
    const float* __restrict__ bias0, const float* __restrict__ bias1,
    const float* __restrict__ bias2, float* __restrict__ y2) {
  __shared__ char lds[81920];  // 64 KB act frags + 16 KB layer2 scratch
  char* buf = lds;
  float* scratch = (float*)(lds + 65536);
  int tid = threadIdx.x, w = tid >> 6, lane = tid & 63;
  int lo = lane * 16;

  // XCD-chunked bijective swizzle: 1600 = 8 XCD * 200; same-es blocks share L2.
  int bid = blockIdx.x;
  int lin = (bid & 7) * 200 + (bid >> 3);
  int es = lin >> 5, b0 = (lin & 31) * 128;
  int og = w & 3, bg = w >> 2;

  // stage state tile [128 rows][256] as 64 B-frags (frag F = bt*16 + kt2)
#pragma unroll
  for (int it = 0; it < 8; ++it) {
    int F = it * 8 + w, bt = F >> 4, kt2 = F & 15;
    const unsigned short* src =
        stateb + (size_t)(b0 + bt * 32 + (lane & 31)) * 256 + kt2 * 16 + (lane >> 5) * 8;
    *(u16x8*)(buf + F * 1024 + lo) = *(const u16x8*)src;
  }
  __syncthreads();

  mlp_layer32(W0f + (size_t)es * 131072, bias0 + es * 256, og, bg, buf, lane);
  mlp_layer32(W1f + (size_t)es * 131072, bias1 + es * 256, og, bg, buf, lane);

  // layer 2 (O padded to 32): wave = (bt2 = w&3, K-half kh = w>>2)
  int bt2 = w & 3, kh = w >> 2;
  f32x16 acc2;
#pragma unroll
  for (int c = 0; c < 16; ++c) acc2[c] = 0.f;
  const char* b2k = buf + (size_t)bt2 * 16384 + kh * 8192;
  const char* w2p = W2f + (size_t)es * 16384 + kh * 8192;
#pragma unroll
  for (int k = 0; k < 8; ++k) {
    bf16x8 a = *(const bf16x8*)(w2p + k * 1024 + lo);
    bf16x8 bb = *(const bf16x8*)(b2k + k * 1024 + lo);
    acc2 = mfma32(a, bb, acc2);
  }
  if (kh == 1) {
#pragma unroll
    for (int q = 0; q < 4; ++q) {
      f32x4 v = {acc2[4 * q], acc2[4 * q + 1], acc2[4 * q + 2], acc2[4 * q + 3]};
      *(f32x4*)(scratch + (size_t)((bt2 * 4 + q) * 64 + lane) * 4) = v;
    }
  }
  __syncthreads();
  if (kh == 0) {
    int hi = lane >> 5, bcol = lane & 31;
    int b_idx = b0 + bt2 * 32 + bcol;
    float* yp = y2 + ((size_t)es * 4096 + b_idx) * 20;
    float s[16];
#pragma unroll
    for (int q = 0; q < 4; ++q) {
      f32x4 p = *(const f32x4*)(scratch + (size_t)((bt2 * 4 + q) * 64 + lane) * 4);
      f32x4 bv = *(const f32x4*)(bias2 + es * 32 + 8 * q + 4 * hi);
      s[4 * q + 0] = acc2[4 * q + 0] + p.x + bv.x;
      s[4 * q + 1] = acc2[4 * q + 1] + p.y + bv.y;
      s[4 * q + 2] = acc2[4 * q + 2] + p.z + bv.z;
      s[4 * q + 3] = acc2[4 * q + 3] + p.w + bv.w;
    }
    if (hi == 0) {
      f32x4 v0 = {s[0], s[1], s[2], s[3]};
      f32x4 v1 = {s[4], s[5], s[6], s[7]};
      float2 v2 = {s[8], s[9]};
      *(f32x4*)(yp) = v0;        // o 0..3
      *(f32x4*)(yp + 8) = v1;    // o 8..11
      *(float2*)(yp + 16) = v2;  // o 16,17
    } else {
      f32x4 v0 = {s[0], s[1], s[2], s[3]};
      f32x4 v1 = {s[4], s[5], s[6], s[7]};
      *(f32x4*)(yp + 4) = v0;    // o 4..7
      *(f32x4*)(yp + 12) = v1;   // o 12..15
    }
  }
}

// ------------- heads (with fused ensemble stats + KL final) ------------------
__global__ __launch_bounds__(256) void heads_kernel(
    const float* __restrict__ y2, const float* __restrict__ partials,
    const float* __restrict__ uh_w1, const float* __restrict__ uh_b1,
    const float* __restrict__ uh_w2, const float* __restrict__ uh_b2,
    const float* __restrict__ rh_w1, const float* __restrict__ rh_b1,
    const float* __restrict__ rh_w2, const float* __restrict__ rh_b2,
    float* __restrict__ out) {
  int b = blockIdx.x, t = threadIdx.x;
  if (b == 4096) {  // KL final reduce
    if (t < 64) {
      float acc = 0.f;
      for (int i = t; i < 4019; i += 64) acc += partials[i];
#pragma unroll
      for (int m = 32; m >= 1; m >>= 1) acc += __shfl_xor(acc, m);
      if (t == 0) out[446464] = acc * 0.2f;
    }
    return;
  }

  __shared__ float ysh[1000];
  __shared__ float qsE[90];
  __shared__ float rin[54];
  __shared__ float h[256];

  // gather this row's 50 es-chunks of 20 floats (5 x f32x4 each)
  if (t < 250) {
    int es_t = t / 5, part = t - es_t * 5;
    *(f32x4*)(ysh + t * 4) =
        *(const f32x4*)(y2 + ((size_t)es_t * 4096 + b) * 20 + part * 4);
  }
  __syncthreads();

  // per-(a,e) MC mean over s
  if (t < 90) {
    int a = t / 5, e = t - (t / 5) * 5;
    float v = 0.f;
#pragma unroll
    for (int s = 0; s < 10; ++s) v += ysh[(e * 10 + s) * 20 + a];
    qsE[t] = v * 0.1f;
  }
  __syncthreads();
  if (t < 18) {
    float qs = 0.f, qq = 0.f;
#pragma unroll
    for (int e = 0; e < 5; ++e) {
      float v = qsE[t * 5 + e];
      qs += v;
      qq += v * v;
    }
    float mean = qs * 0.2f;
    float var = fmaxf((qq - 5.f * mean * mean) * 0.25f, 0.f);
    rin[t] = mean;
    rin[18 + t] = var;
    out[b * 18 + t] = mean;
    out[73728 + b * 18 + t] = var;
  }
  __syncthreads();

  // uncertainty hidden layer
  {
    float acc = uh_b1[t];
    const f32x4* wr = (const f32x4*)(uh_w1 + t * 36);
#pragma unroll
    for (int j = 0; j < 9; ++j) {
      f32x4 wv = wr[j];
      acc += wv.x * rin[j * 4] + wv.y * rin[j * 4 + 1] + wv.z * rin[j * 4 + 2] +
             wv.w * rin[j * 4 + 3];
    }
    h[t] = fmaxf(acc, 0.f);
  }
  __syncthreads();

  int w = t >> 6, lane = t & 63;
  for (int idx = 0; idx < 5; ++idx) {
    int a = idx * 4 + w;
    if (a < 18) {
      float p = 0.f;
#pragma unroll
      for (int j = 0; j < 4; ++j) p += h[lane + 64 * j] * uh_w2[a * 256 + lane + 64 * j];
#pragma unroll
      for (int m = 32; m >= 1; m >>= 1) p += __shfl_xor(p, m);
      if (lane == 0) {
        float alea = softplus_f(p + uh_b2[a]);
        float qm = rin[a], epi = rin[18 + a];
        float tu = epi + alea;
        float s2 = 2.f * sqrtf(tu);
        out[2 * 73728 + b * 18 + a] = alea;
        out[3 * 73728 + b * 18 + a] = tu;
        out[4 * 73728 + b * 18 + a] = qm - s2;
        out[5 * 73728 + b * 18 + a] = qm + s2;
        rin[36 + a] = alea;
      }
    }
  }
  __syncthreads();

  // risk hidden layer
  {
    float acc = rh_b1[t];
    const float2* wr2 = (const float2*)(rh_w1 + t * 54);
#pragma unroll
    for (int j = 0; j < 27; ++j) {
      float2 wv = wr2[j];
      acc += wv.x * rin[j * 2] + wv.y * rin[j * 2 + 1];
    }
    h[t] = fmaxf(acc, 0.f);
  }
  __syncthreads();
  if (w == 0) {
    float p = 0.f;
#pragma unroll
    for (int j = 0; j < 4; ++j) p += h[lane + 64 * j] * rh_w2[lane + 64 * j];
#pragma unroll
    for (int m = 32; m >= 1; m >>= 1) p += __shfl_xor(p, m);
    if (lane == 0) out[6 * 73728 + b] = p + rh_b2[0];
  }
}

// ------------------------------ launch ---------------------------------------
extern "C" void kernel_launch(void* const* d_in, const int* in_sizes, int n_in,
                              void* d_out, int out_size, void* d_ws, size_t ws_size,
                              hipStream_t stream) {
  const float* state = (const float*)d_in[0];
  const float* w_mu0 = (const float*)d_in[2];
  const float* w_rho0 = (const float*)d_in[3];
  const float* b_mu0 = (const float*)d_in[4];
  const float* b_rho0 = (const float*)d_in[5];
  const float* w_eps0 = (const float*)d_in[6];
  const float* b_eps0 = (const float*)d_in[7];
  const float* w_mu1 = (const float*)d_in[8];
  const float* w_rho1 = (const float*)d_in[9];
  const float* b_mu1 = (const float*)d_in[10];
  const float* b_rho1 = (const float*)d_in[11];
  const float* w_eps1 = (const float*)d_in[12];
  const float* b_eps1 = (const float*)d_in[13];
  const float* w_mu2 = (const float*)d_in[14];
  const float* w_rho2 = (const float*)d_in[15];
  const float* b_mu2 = (const float*)d_in[16];
  const float* b_rho2 = (const float*)d_in[17];
  const float* w_eps2 = (const float*)d_in[18];
  const float* b_eps2 = (const float*)d_in[19];
  const float* uh_w1 = (const float*)d_in[20];
  const float* uh_b1 = (const float*)d_in[21];
  const float* uh_w2 = (const float*)d_in[22];
  const float* uh_b2 = (const float*)d_in[23];
  const float* rh_w1 = (const float*)d_in[24];
  const float* rh_b1 = (const float*)d_in[25];
  const float* rh_w2 = (const float*)d_in[26];
  const float* rh_b2 = (const float*)d_in[27];
  float* out = (float*)d_out;

  char* ws = (char*)d_ws;
  unsigned short* stateb = (unsigned short*)ws;          // 2 MB
  char* W0f = ws + 2097152;                              // 6.5536 MB
  char* W1f = W0f + 6553600;
  char* W2f = W1f + 6553600;                             // 0.8192 MB
  float* bias0 = (float*)(W2f + 819200);                 // 12800 f
  float* bias1 = bias0 + 12800;
  float* bias2 = bias1 + 12800;                          // 1600 f
  float* y2 = bias2 + 1600;                              // 50*4096*20 f
  float* klpart = y2 + (size_t)50 * 4096 * 20;           // 4019 f

  prep_kernel<<<4019, 256, 0, stream>>>(
      state, stateb, w_mu0, w_rho0, w_eps0, W0f, w_mu1, w_rho1, w_eps1, W1f,
      w_mu2, w_rho2, w_eps2, W2f, b_mu0, b_rho0, b_eps0, b_mu1, b_rho1, b_eps1,
      b_mu2, b_rho2, b_eps2, bias0, bias1, bias2, klpart);
  mlp_fused<<<1600, 512, 0, stream>>>(stateb, W0f, W1f, W2f, bias0, bias1,
                                      bias2, y2);
  heads_kernel<<<4097, 256, 0, stream>>>(y2, klpart, uh_w1, uh_b1, uh_w2, uh_b2,
                                         rh_w1, rh_b1, rh_w2, rh_b2, out);
}

// Round 7
// 105.927 us; speedup vs baseline: 1.3399x; 1.3399x over previous
//
#include <hip/hip_runtime.h>
#include <hip/hip_bf16.h>

// ---------------------------------------------------------------------------
// UncertaintyAwareQNetwork: E=5 ensemble x NS=10 MC samples, B=4096 rows.
// Pipeline (3 dispatches):
//   prep:   state->bf16, realized weights (32x32x16 MFMA-frag-major) + KL
//   mlp:    fused 3-layer kernel, 64-row x 256-out tile, 4 waves/block,
//           40 KB LDS -> 4 blocks/CU (4 barrier domains), XCD swizzle
//   heads:  ensemble stats + uncertainty/risk heads + KL final, 8 rows/block
// y2 layout: [es][b][20] f32 -> mlp blocks write contiguous full lines.
// ---------------------------------------------------------------------------

typedef __bf16 bf16x8 __attribute__((ext_vector_type(8)));
typedef float f32x4 __attribute__((ext_vector_type(4)));
typedef float f32x16 __attribute__((ext_vector_type(16)));
typedef unsigned short u16x4 __attribute__((ext_vector_type(4)));
typedef unsigned short u16x8 __attribute__((ext_vector_type(8)));

__device__ __forceinline__ unsigned short f2bf(float f) {
  unsigned int u = __builtin_bit_cast(unsigned int, f);
  u += 0x7fffu + ((u >> 16) & 1u);
  return (unsigned short)(u >> 16);
}

__device__ __forceinline__ float softplus_f(float x) {
  return (x > 20.f) ? x : __logf(1.f + __expf(x));
}

__device__ __forceinline__ float klterm(float m, float sg) {
  return -__logf(sg) + (sg * sg + m * m) * 0.5f - 0.5f;
}

__device__ __forceinline__ f32x16 mfma32(bf16x8 a, bf16x8 b, f32x16 c) {
  return __builtin_amdgcn_mfma_f32_32x32x16_bf16(a, b, c, 0, 0, 0);
}

// ------------------- prep bodies (fused into one kernel) --------------------

__device__ __forceinline__ void scvt_body(int gid, const float* __restrict__ s,
                                          unsigned short* __restrict__ d) {
  const f32x4* p = (const f32x4*)(s + (size_t)gid * 8);
  f32x4 x0 = p[0], x1 = p[1];
  u16x8 v = {f2bf(x0.x), f2bf(x0.y), f2bf(x0.z), f2bf(x0.w),
             f2bf(x1.x), f2bf(x1.y), f2bf(x1.z), f2bf(x1.w)};
  *(u16x8*)(d + (size_t)gid * 8) = v;
}

// 32x32x16 A-frag layout: frag id = (es*(OPAD/32) + osub)*16 + kt2;
// lane l = (o&31) + 32*k_octet holds W[o][k = kt2*16 + k_octet*8 + 0..7].
template <int O, int OPAD>
__device__ __forceinline__ float wgen_body(int gid, const float* __restrict__ wmu,
                                           const float* __restrict__ wrho,
                                           const float* __restrict__ weps,
                                           char* __restrict__ wf) {
  int es = gid / (OPAD * 32);
  int rem = gid - es * (OPAD * 32);
  int o = rem >> 5;
  int i8 = (rem & 31) * 8;
  int e = es / 10, s = es - e * 10;
  float v[8];
  float kl = 0.f;
  if (O == OPAD || o < O) {
    const float* mu = wmu + ((size_t)(e * O + o)) * 256 + i8;
    const float* rho = wrho + ((size_t)(e * O + o)) * 256 + i8;
    const float* eps = weps + ((size_t)((e * 10 + s) * O + o)) * 256 + i8;
    float mv[8], rv[8], ev[8];
    *(f32x4*)(mv) = ((const f32x4*)mu)[0];
    *(f32x4*)(mv + 4) = ((const f32x4*)mu)[1];
    *(f32x4*)(rv) = ((const f32x4*)rho)[0];
    *(f32x4*)(rv + 4) = ((const f32x4*)rho)[1];
    *(f32x4*)(ev) = ((const f32x4*)eps)[0];
    *(f32x4*)(ev + 4) = ((const f32x4*)eps)[1];
#pragma unroll
    for (int j = 0; j < 8; ++j) {
      float m = mv[j];
      float sg = softplus_f(rv[j]);
      v[j] = m + sg * ev[j];
      if (s == 0) kl += klterm(m, sg);
    }
  } else {
#pragma unroll
    for (int j = 0; j < 8; ++j) v[j] = 0.f;
  }
  u16x8 pk = {f2bf(v[0]), f2bf(v[1]), f2bf(v[2]), f2bf(v[3]),
              f2bf(v[4]), f2bf(v[5]), f2bf(v[6]), f2bf(v[7])};
  int osub = o >> 5, om = o & 31, kt2 = i8 >> 4, hi = (i8 >> 3) & 1;
  int lane = om + 32 * hi;
  *(u16x8*)(wf + (size_t)(((es * (OPAD / 32) + osub) * 16 + kt2) * 64 + lane) * 16) = pk;
  return kl;
}

__global__ __launch_bounds__(256) void prep_kernel(
    const float* __restrict__ state, unsigned short* __restrict__ stateb,
    const float* __restrict__ wmu0, const float* __restrict__ wrho0,
    const float* __restrict__ weps0, char* __restrict__ W0f,
    const float* __restrict__ wmu1, const float* __restrict__ wrho1,
    const float* __restrict__ weps1, char* __restrict__ W1f,
    const float* __restrict__ wmu2, const float* __restrict__ wrho2,
    const float* __restrict__ weps2, char* __restrict__ W2f,
    const float* __restrict__ bmu0, const float* __restrict__ brho0,
    const float* __restrict__ beps0, const float* __restrict__ bmu1,
    const float* __restrict__ brho1, const float* __restrict__ beps1,
    const float* __restrict__ bmu2, const float* __restrict__ brho2,
    const float* __restrict__ beps2, float* __restrict__ bias0,
    float* __restrict__ bias1, float* __restrict__ bias2,
    float* __restrict__ partials) {
  int bid = blockIdx.x, t = threadIdx.x;
  float kl = 0.f;
  if (bid < 512) {
    scvt_body(bid * 256 + t, state, stateb);
  } else if (bid < 2112) {
    kl = wgen_body<256, 256>((bid - 512) * 256 + t, wmu0, wrho0, weps0, W0f);
  } else if (bid < 3712) {
    kl = wgen_body<256, 256>((bid - 2112) * 256 + t, wmu1, wrho1, weps1, W1f);
  } else if (bid < 3912) {
    kl = wgen_body<18, 32>((bid - 3712) * 256 + t, wmu2, wrho2, weps2, W2f);
  } else {
    int gid = (bid - 3912) * 256 + t;
    if (gid < 12800) {
      int es = gid >> 8, o = gid & 255, e = es / 10, s = es - e * 10;
      float m = bmu0[e * 256 + o];
      float sg = softplus_f(brho0[e * 256 + o]);
      bias0[gid] = m + sg * beps0[(e * 10 + s) * 256 + o];
      if (s == 0) kl = klterm(m, sg);
    } else if (gid < 25600) {
      int id = gid - 12800;
      int es = id >> 8, o = id & 255, e = es / 10, s = es - e * 10;
      float m = bmu1[e * 256 + o];
      float sg = softplus_f(brho1[e * 256 + o]);
      bias1[id] = m + sg * beps1[(e * 10 + s) * 256 + o];
      if (s == 0) kl = klterm(m, sg);
    } else if (gid < 27200) {
      int id = gid - 25600;
      int es = id >> 5, o = id & 31, e = es / 10, s = es - e * 10;
      if (o < 18) {
        float m = bmu2[e * 18 + o];
        float sg = softplus_f(brho2[e * 18 + o]);
        bias2[id] = m + sg * beps2[(e * 10 + s) * 18 + o];
        if (s == 0) kl = klterm(m, sg);
      } else {
        bias2[id] = 0.f;
      }
    }
  }
  // uniform block reduce of kl partials
#pragma unroll
  for (int m = 32; m >= 1; m >>= 1) kl += __shfl_xor(kl, m);
  __shared__ float wsum[4];
  if ((t & 63) == 0) wsum[t >> 6] = kl;
  __syncthreads();
  if (t == 0) partials[bid] = wsum[0] + wsum[1] + wsum[2] + wsum[3];
}

// ------------------------------ fused MLP ------------------------------------
// Block tile: 64 rows x 256 outs, 4 waves (og = w in 0..3), wave tile
// 64 outs x 64 rows as 2x2 of 32x32 -> 4 f32x16 acc. 40 KB LDS -> 4 blocks/CU.
// Activation LDS: 32 frags (bt 0..1 x kt2 0..15), frag = 1 KB, lane*16 linear.
// B-frag: lane l holds x[b = bt*32 + (l&31)][k = kt2*16 + (l>>5)*8 + 0..7].
__device__ __forceinline__ void mlp_layer32(const char* __restrict__ wA,
                                            const float* __restrict__ bias_es,
                                            int og, char* __restrict__ buf,
                                            int lane) {
  const char* a0p = wA + (size_t)(2 * og) * 16384;
  const char* a1p = a0p + 16384;
  const char* b0p = buf;
  const char* b1p = buf + 16384;
  int lo = lane * 16;
  f32x16 acc00, acc01, acc10, acc11;
#pragma unroll
  for (int c = 0; c < 16; ++c) {
    acc00[c] = 0.f; acc01[c] = 0.f; acc10[c] = 0.f; acc11[c] = 0.f;
  }

  bf16x8 a0c = *(const bf16x8*)(a0p + lo);
  bf16x8 a1c = *(const bf16x8*)(a1p + lo);
  bf16x8 b0c = *(const bf16x8*)(b0p + lo);
  bf16x8 b1c = *(const bf16x8*)(b1p + lo);
#pragma unroll
  for (int kp = 0; kp < 8; ++kp) {
    bf16x8 a0n = *(const bf16x8*)(a0p + (2 * kp + 1) * 1024 + lo);
    bf16x8 a1n = *(const bf16x8*)(a1p + (2 * kp + 1) * 1024 + lo);
    bf16x8 b0n = *(const bf16x8*)(b0p + (2 * kp + 1) * 1024 + lo);
    bf16x8 b1n = *(const bf16x8*)(b1p + (2 * kp + 1) * 1024 + lo);
    __builtin_amdgcn_s_setprio(1);
    acc00 = mfma32(a0c, b0c, acc00);
    acc01 = mfma32(a0c, b1c, acc01);
    acc10 = mfma32(a1c, b0c, acc10);
    acc11 = mfma32(a1c, b1c, acc11);
    __builtin_amdgcn_s_setprio(0);
    if (kp < 7) {
      a0c = *(const bf16x8*)(a0p + (2 * kp + 2) * 1024 + lo);
      a1c = *(const bf16x8*)(a1p + (2 * kp + 2) * 1024 + lo);
      b0c = *(const bf16x8*)(b0p + (2 * kp + 2) * 1024 + lo);
      b1c = *(const bf16x8*)(b1p + (2 * kp + 2) * 1024 + lo);
    }
    __builtin_amdgcn_s_setprio(1);
    acc00 = mfma32(a0n, b0n, acc00);
    acc01 = mfma32(a0n, b1n, acc01);
    acc10 = mfma32(a1n, b0n, acc10);
    acc11 = mfma32(a1n, b1n, acc11);
    __builtin_amdgcn_s_setprio(0);
  }
  __syncthreads();  // all reads of buf complete before in-place overwrite

  // epilogue: bias+relu+bf16, packed into next layer's B-frag layout.
  // C/D: col b = lane&31, row o_local = (reg&3) + 8*(reg>>2) + 4*(lane>>5).
  int hi = lane >> 5, bcol = lane & 31;
  auto epi = [&](const f32x16& A, int i, int j) {
    int obt = og * 64 + i * 32;
    char* fb = buf + (size_t)(j * 16) * 1024;
#pragma unroll
    for (int q = 0; q < 4; ++q) {
      int o0 = obt + 8 * q + 4 * hi;
      f32x4 bv = *(const f32x4*)(bias_es + o0);
      float v0 = fmaxf(A[4 * q + 0] + bv.x, 0.f);
      float v1 = fmaxf(A[4 * q + 1] + bv.y, 0.f);
      float v2 = fmaxf(A[4 * q + 2] + bv.z, 0.f);
      float v3 = fmaxf(A[4 * q + 3] + bv.w, 0.f);
      u16x4 pk = {f2bf(v0), f2bf(v1), f2bf(v2), f2bf(v3)};
      int kt2t = o0 >> 4;
      *(u16x4*)(fb + kt2t * 1024 + (bcol + 32 * (q & 1)) * 16 + 8 * hi) = pk;
    }
  };
  epi(acc00, 0, 0);
  epi(acc01, 0, 1);
  epi(acc10, 1, 0);
  epi(acc11, 1, 1);
  __syncthreads();  // writes visible before next layer reads
}

__global__ __launch_bounds__(256, 4) void mlp_fused(
    const unsigned short* __restrict__ stateb, const char* __restrict__ W0f,
    const char* __restrict__ W1f, const char* __restrict__ W2f,
    const float* __restrict__ bias0, const float* __restrict__ bias1,
    const float* __restrict__ bias2, float* __restrict__ y2) {
  __shared__ char lds[40960];  // 32 KB act frags + 8 KB layer2 scratch
  char* buf = lds;
  float* scratch = (float*)(lds + 32768);
  int tid = threadIdx.x, w = tid >> 6, lane = tid & 63;
  int lo = lane * 16;

  // XCD-chunked bijective swizzle: 3200 = 8 XCD * 400; same-es blocks share L2.
  int bid = blockIdx.x;
  int lin = (bid & 7) * 400 + (bid >> 3);
  int es = lin >> 6, b0 = (lin & 63) * 64;
  int og = w;

  // stage state tile [64 rows][256] as 32 B-frags (frag F = bt*16 + kt2)
#pragma unroll
  for (int it = 0; it < 8; ++it) {
    int F = it * 4 + w, bt = F >> 4, kt2 = F & 15;
    const unsigned short* src =
        stateb + (size_t)(b0 + bt * 32 + (lane & 31)) * 256 + kt2 * 16 + (lane >> 5) * 8;
    *(u16x8*)(buf + F * 1024 + lo) = *(const u16x8*)src;
  }
  __syncthreads();

  mlp_layer32(W0f + (size_t)es * 131072, bias0 + es * 256, og, buf, lane);
  mlp_layer32(W1f + (size_t)es * 131072, bias1 + es * 256, og, buf, lane);

  // layer 2 (O padded to 32): wave = (bt2 = w&1, K-half kh = w>>1)
  int bt2 = w & 1, kh = w >> 1;
  f32x16 acc2;
#pragma unroll
  for (int c = 0; c < 16; ++c) acc2[c] = 0.f;
  const char* b2k = buf + (size_t)bt2 * 16384 + kh * 8192;
  const char* w2p = W2f + (size_t)es * 16384 + kh * 8192;
#pragma unroll
  for (int k = 0; k < 8; ++k) {
    bf16x8 a = *(const bf16x8*)(w2p + k * 1024 + lo);
    bf16x8 bb = *(const bf16x8*)(b2k + k * 1024 + lo);
    acc2 = mfma32(a, bb, acc2);
  }
  if (kh == 1) {
#pragma unroll
    for (int q = 0; q < 4; ++q) {
      f32x4 v = {acc2[4 * q], acc2[4 * q + 1], acc2[4 * q + 2], acc2[4 * q + 3]};
      *(f32x4*)(scratch + (size_t)((bt2 * 4 + q) * 64 + lane) * 4) = v;
    }
  }
  __syncthreads();
  if (kh == 0) {
    int hi = lane >> 5, bcol = lane & 31;
    int b_idx = b0 + bt2 * 32 + bcol;
    float* yp = y2 + ((size_t)es * 4096 + b_idx) * 20;
    float s[16];
#pragma unroll
    for (int q = 0; q < 4; ++q) {
      f32x4 p = *(const f32x4*)(scratch + (size_t)((bt2 * 4 + q) * 64 + lane) * 4);
      f32x4 bv = *(const f32x4*)(bias2 + es * 32 + 8 * q + 4 * hi);
      s[4 * q + 0] = acc2[4 * q + 0] + p.x + bv.x;
      s[4 * q + 1] = acc2[4 * q + 1] + p.y + bv.y;
      s[4 * q + 2] = acc2[4 * q + 2] + p.z + bv.z;
      s[4 * q + 3] = acc2[4 * q + 3] + p.w + bv.w;
    }
    if (hi == 0) {
      f32x4 v0 = {s[0], s[1], s[2], s[3]};
      f32x4 v1 = {s[4], s[5], s[6], s[7]};
      float2 v2 = {s[8], s[9]};
      *(f32x4*)(yp) = v0;        // o 0..3
      *(f32x4*)(yp + 8) = v1;    // o 8..11
      *(float2*)(yp + 16) = v2;  // o 16,17
    } else {
      f32x4 v0 = {s[0], s[1], s[2], s[3]};
      f32x4 v1 = {s[4], s[5], s[6], s[7]};
      *(f32x4*)(yp + 4) = v0;    // o 4..7
      *(f32x4*)(yp + 12) = v1;   // o 12..15
    }
  }
}

// ------------- heads: 8 rows per block + KL final ----------------------------
__global__ __launch_bounds__(256) void heads_kernel(
    const float* __restrict__ y2, const float* __restrict__ partials,
    const float* __restrict__ uh_w1, const float* __restrict__ uh_b1,
    const float* __restrict__ uh_w2, const float* __restrict__ uh_b2,
    const float* __restrict__ rh_w1, const float* __restrict__ rh_b1,
    const float* __restrict__ rh_w2, const float* __restrict__ rh_b2,
    float* __restrict__ out) {
  int bid = blockIdx.x, t = threadIdx.x;
  if (bid == 512) {  // KL final reduce
    if (t < 64) {
      float acc = 0.f;
      for (int i = t; i < 4019; i += 64) acc += partials[i];
#pragma unroll
      for (int m = 32; m >= 1; m >>= 1) acc += __shfl_xor(acc, m);
      if (t == 0) out[446464] = acc * 0.2f;
    }
    return;
  }
  int b0 = bid * 8;

  __shared__ float ysh[8][1004];  // padded rows
  __shared__ float qsE[8][90];
  __shared__ float rin[8][56];
  __shared__ float h[8][260];

  // coalesced gather: 8 rows x 250 f32x4
  for (int i = t; i < 2000; i += 256) {
    int r = i / 250, c = i - r * 250;
    int es_t = c / 5, part = c - es_t * 5;
    *(f32x4*)(&ysh[r][c * 4]) =
        *(const f32x4*)(y2 + ((size_t)es_t * 4096 + b0 + r) * 20 + part * 4);
  }
  __syncthreads();

  // per-(row, a, e) MC mean over s
  for (int i = t; i < 720; i += 256) {
    int r = i / 90, ae = i - r * 90;
    int a = ae / 5, e = ae - a * 5;
    float v = 0.f;
#pragma unroll
    for (int s = 0; s < 10; ++s) v += ysh[r][(e * 10 + s) * 20 + a];
    qsE[r][ae] = v * 0.1f;
  }
  __syncthreads();

  if (t < 144) {
    int r = t / 18, a = t - (t / 18) * 18;
    float qs = 0.f, qq = 0.f;
#pragma unroll
    for (int e = 0; e < 5; ++e) {
      float v = qsE[r][a * 5 + e];
      qs += v;
      qq += v * v;
    }
    float mean = qs * 0.2f;
    float var = fmaxf((qq - 5.f * mean * mean) * 0.25f, 0.f);
    rin[r][a] = mean;
    rin[r][18 + a] = var;
    out[(b0 + r) * 18 + a] = mean;
    out[73728 + (b0 + r) * 18 + a] = var;
  }
  __syncthreads();

  // uncertainty hidden layer: weight row loaded once, reused for 8 rows
  {
    f32x4 wv[9];
    const f32x4* wr = (const f32x4*)(uh_w1 + t * 36);
#pragma unroll
    for (int j = 0; j < 9; ++j) wv[j] = wr[j];
    float bb = uh_b1[t];
#pragma unroll
    for (int r = 0; r < 8; ++r) {
      float acc = bb;
#pragma unroll
      for (int j = 0; j < 9; ++j) {
        acc += wv[j].x * rin[r][j * 4] + wv[j].y * rin[r][j * 4 + 1] +
               wv[j].z * rin[r][j * 4 + 2] + wv[j].w * rin[r][j * 4 + 3];
      }
      h[r][t] = fmaxf(acc, 0.f);
    }
  }
  __syncthreads();

  // uncertainty output: (row, a) pairs, full 256-dot each
  if (t < 144) {
    int r = t / 18, a = t - (t / 18) * 18;
    float p = 0.f;
    const f32x4* w2r = (const f32x4*)(uh_w2 + a * 256);
#pragma unroll
    for (int j = 0; j < 64; ++j) {
      f32x4 wv = w2r[j];
      f32x4 hv = *(const f32x4*)(&h[r][j * 4]);
      p += wv.x * hv.x + wv.y * hv.y + wv.z * hv.z + wv.w * hv.w;
    }
    float alea = softplus_f(p + uh_b2[a]);
    float qm = rin[r][a], epi = rin[r][18 + a];
    float tu = epi + alea;
    float s2 = 2.f * sqrtf(tu);
    int b = b0 + r;
    out[2 * 73728 + b * 18 + a] = alea;
    out[3 * 73728 + b * 18 + a] = tu;
    out[4 * 73728 + b * 18 + a] = qm - s2;
    out[5 * 73728 + b * 18 + a] = qm + s2;
    rin[r][36 + a] = alea;
  }
  __syncthreads();

  // risk hidden layer
  {
    float w1v[54];
    const float2* wr2 = (const float2*)(rh_w1 + t * 54);
#pragma unroll
    for (int j = 0; j < 27; ++j) {
      float2 wv = wr2[j];
      w1v[j * 2] = wv.x;
      w1v[j * 2 + 1] = wv.y;
    }
    float bb = rh_b1[t];
#pragma unroll
    for (int r = 0; r < 8; ++r) {
      float acc = bb;
#pragma unroll
      for (int j = 0; j < 54; ++j) acc += w1v[j] * rin[r][j];
      h[r][t] = fmaxf(acc, 0.f);
    }
  }
  __syncthreads();

  // risk output: one thread per row
  if (t < 8) {
    float p = 0.f;
    const f32x4* w2r = (const f32x4*)(rh_w2);
#pragma unroll
    for (int j = 0; j < 64; ++j) {
      f32x4 wv = w2r[j];
      f32x4 hv = *(const f32x4*)(&h[t][j * 4]);
      p += wv.x * hv.x + wv.y * hv.y + wv.z * hv.z + wv.w * hv.w;
    }
    out[6 * 73728 + b0 + t] = p + rh_b2[0];
  }
}

// ------------------------------ launch ---------------------------------------
extern "C" void kernel_launch(void* const* d_in, const int* in_sizes, int n_in,
                              void* d_out, int out_size, void* d_ws, size_t ws_size,
                              hipStream_t stream) {
  const float* state = (const float*)d_in[0];
  const float* w_mu0 = (const float*)d_in[2];
  const float* w_rho0 = (const float*)d_in[3];
  const float* b_mu0 = (const float*)d_in[4];
  const float* b_rho0 = (const float*)d_in[5];
  const float* w_eps0 = (const float*)d_in[6];
  const float* b_eps0 = (const float*)d_in[7];
  const float* w_mu1 = (const float*)d_in[8];
  const float* w_rho1 = (const float*)d_in[9];
  const float* b_mu1 = (const float*)d_in[10];
  const float* b_rho1 = (const float*)d_in[11];
  const float* w_eps1 = (const float*)d_in[12];
  const float* b_eps1 = (const float*)d_in[13];
  const float* w_mu2 = (const float*)d_in[14];
  const float* w_rho2 = (const float*)d_in[15];
  const float* b_mu2 = (const float*)d_in[16];
  const float* b_rho2 = (const float*)d_in[17];
  const float* w_eps2 = (const float*)d_in[18];
  const float* b_eps2 = (const float*)d_in[19];
  const float* uh_w1 = (const float*)d_in[20];
  const float* uh_b1 = (const float*)d_in[21];
  const float* uh_w2 = (const float*)d_in[22];
  const float* uh_b2 = (const float*)d_in[23];
  const float* rh_w1 = (const float*)d_in[24];
  const float* rh_b1 = (const float*)d_in[25];
  const float* rh_w2 = (const float*)d_in[26];
  const float* rh_b2 = (const float*)d_in[27];
  float* out = (float*)d_out;

  char* ws = (char*)d_ws;
  unsigned short* stateb = (unsigned short*)ws;          // 2 MB
  char* W0f = ws + 2097152;                              // 6.5536 MB
  char* W1f = W0f + 6553600;
  char* W2f = W1f + 6553600;                             // 0.8192 MB
  float* bias0 = (float*)(W2f + 819200);                 // 12800 f
  float* bias1 = bias0 + 12800;
  float* bias2 = bias1 + 12800;                          // 1600 f
  float* y2 = bias2 + 1600;                              // 50*4096*20 f
  float* klpart = y2 + (size_t)50 * 4096 * 20;           // 4019 f

  prep_kernel<<<4019, 256, 0, stream>>>(
      state, stateb, w_mu0, w_rho0, w_eps0, W0f, w_mu1, w_rho1, w_eps1, W1f,
      w_mu2, w_rho2, w_eps2, W2f, b_mu0, b_rho0, b_eps0, b_mu1, b_rho1, b_eps1,
      b_mu2, b_rho2, b_eps2, bias0, bias1, bias2, klpart);
  mlp_fused<<<3200, 256, 0, stream>>>(stateb, W0f, W1f, W2f, bias0, bias1,
                                      bias2, y2);
  heads_kernel<<<513, 256, 0, stream>>>(y2, klpart, uh_w1, uh_b1, uh_w2, uh_b2,
                                        rh_w1, rh_b1, rh_w2, rh_b2, out);
}